// Round 4
// baseline (1378.122 us; speedup 1.0000x reference)
//
#include <hip/hip_runtime.h>

// 0.8*dice_loss(pred,target) + 0.2*soft_cldice_loss(pred,target)
// pred/target: (64,1,512,512) fp32 -> 1 fp32 scalar.
//
// soft_skeletonize = 10x: x = relu(x - relu(dil3(ero3(x)) - ero3(x)))
//   ero3 = 3x3 min-pool, x OOB -> +inf; dil3 = 3x3 max-pool, ero OOB -> -inf
//
// Lessons encoded here:
//  - R1/R2: d_ws is smaller than assumed -> use ZERO d_ws. State lives in
//    module-scope __device__ BSS (g_A/g_B, 64 MiB each) + g_acc.
//  - R3: passing g_A/g_B as kernel args from HOST passes the host shadow
//    address (garbage on device) -> GPU fault. Fix: kernels receive only
//    harness pointers + int selectors; g_A/g_B are resolved in DEVICE code.

#define H 512
#define W 512
#define NIMG 64
#define IMG_ELEMS (H * W)
#define RSTRIPS 4
#define RROWS 128            // rows per wave
#define CSTRIPS 9            // ceil(512/60)
#define CCOLS 60             // valid output cols per wave (64 lanes - 2x2 halo)
#define WAVES_PER_IMG (CSTRIPS * RSTRIPS)   // 36
#define NACC (NIMG * 4 + 3)

// Module-scope device storage: 2 x 64 MiB ping-pong + accumulator.
__device__ float g_A[(size_t)NIMG * IMG_ELEMS];
__device__ float g_B[(size_t)NIMG * IMG_ELEMS];
__device__ float g_acc[NACC];

// Buffer selectors (resolved on device only): 0=ext ptr, 2=g_A, 3=g_B
#define SEL_EXT 0
#define SEL_A 2
#define SEL_B 3

__device__ __forceinline__ float hmin3(float v) {
  return fminf(v, fminf(__shfl_up(v, 1, 64), __shfl_down(v, 1, 64)));
}
__device__ __forceinline__ float hmax3(float v) {
  return fmaxf(v, fmaxf(__shfl_up(v, 1, 64), __shfl_down(v, 1, 64)));
}

// One skeletonize iteration over 64 images: src(sel) -> dst(sel).
__global__ __launch_bounds__(256) void skel_iter(
    const float* __restrict__ ext, int srcSel, int dstSel) {
  const float* src = (srcSel == SEL_EXT) ? ext
                   : (srcSel == SEL_A)   ? (const float*)g_A : (const float*)g_B;
  float* dst = (dstSel == SEL_A) ? g_A : g_B;

  const int wid  = blockIdx.x * 4 + (threadIdx.x >> 6);
  const int lane = threadIdx.x & 63;
  const int img  = wid / WAVES_PER_IMG;
  const int rem  = wid % WAVES_PER_IMG;
  const int cs   = rem / RSTRIPS;
  const int rs   = rem % RSTRIPS;
  const int gc   = cs * CCOLS - 2 + lane;   // global column of this lane

  const float* simg = src + (size_t)img * IMG_ELEMS;
  float* dimg = dst + (size_t)img * IMG_ELEMS;

  const bool colOK = (gc >= 0) && (gc < W);
  const bool outOK = (lane >= 2) && (lane < 62) && (gc < W);  // gc>=0 implied
  const int r0 = rs * RROWS;
  const float PINF = __builtin_inff();

  auto loadx = [&](int r) -> float {            // x OOB -> +inf
    if (colOK && r >= 0 && r < H) return simg[(size_t)r * W + gc];
    return PINF;
  };
  auto ero_row = [&](float vmin, int r) -> float {  // ero OOB position -> -inf
    float e = hmin3(vmin);
    if (!colOK || r < 0 || r >= H) e = -PINF;
    return e;
  };

  float xm = loadx(r0 - 2);
  float xc = loadx(r0 - 1);
  float xp = loadx(r0);
  float e_m = ero_row(fminf(xm, fminf(xc, xp)), r0 - 1);
  xm = xc; xc = xp; xp = loadx(r0 + 1);
  float e_c = ero_row(fminf(xm, fminf(xc, xp)), r0);
  // entering iter r: xc=x[r], xp=x[r+1], e_m=ero[r-1], e_c=ero[r]

  for (int r = r0; r < r0 + RROWS; ++r) {
    float xn = loadx(r + 2);
    float e_p = ero_row(fminf(xc, fminf(xp, xn)), r + 1);
    float dil = hmax3(fmaxf(e_m, fmaxf(e_c, e_p)));
    float nx = fmaxf(xc - fmaxf(dil - e_c, 0.0f), 0.0f);
    if (outOK) dimg[(size_t)r * W + gc] = nx;
    xc = xp; xp = xn;
    e_m = e_c; e_c = e_p;
  }
}

// Final skeletonize iteration (src = g_A always) fused with reduction:
//   g_acc[img*4 + accBase]     += sum(skel * other)
//   g_acc[img*4 + accBase + 1] += sum(skel)
__global__ __launch_bounds__(256) void skel_iter9_reduce(
    const float* __restrict__ other, int accBase) {
  const float* src = g_A;

  const int wid  = blockIdx.x * 4 + (threadIdx.x >> 6);
  const int lane = threadIdx.x & 63;
  const int img  = wid / WAVES_PER_IMG;
  const int rem  = wid % WAVES_PER_IMG;
  const int cs   = rem / RSTRIPS;
  const int rs   = rem % RSTRIPS;
  const int gc   = cs * CCOLS - 2 + lane;

  const float* simg = src + (size_t)img * IMG_ELEMS;
  const float* oimg = other + (size_t)img * IMG_ELEMS;

  const bool colOK = (gc >= 0) && (gc < W);
  const bool outOK = (lane >= 2) && (lane < 62) && (gc < W);
  const int r0 = rs * RROWS;
  const float PINF = __builtin_inff();

  auto loadx = [&](int r) -> float {
    if (colOK && r >= 0 && r < H) return simg[(size_t)r * W + gc];
    return PINF;
  };
  auto ero_row = [&](float vmin, int r) -> float {
    float e = hmin3(vmin);
    if (!colOK || r < 0 || r >= H) e = -PINF;
    return e;
  };

  float xm = loadx(r0 - 2);
  float xc = loadx(r0 - 1);
  float xp = loadx(r0);
  float e_m = ero_row(fminf(xm, fminf(xc, xp)), r0 - 1);
  xm = xc; xc = xp; xp = loadx(r0 + 1);
  float e_c = ero_row(fminf(xm, fminf(xc, xp)), r0);

  float sum_so = 0.0f, sum_s = 0.0f;
  for (int r = r0; r < r0 + RROWS; ++r) {
    float xn = loadx(r + 2);
    float e_p = ero_row(fminf(xc, fminf(xp, xn)), r + 1);
    float dil = hmax3(fmaxf(e_m, fmaxf(e_c, e_p)));
    float nx = fmaxf(xc - fmaxf(dil - e_c, 0.0f), 0.0f);
    if (outOK) {                   // masked lanes may hold inf/NaN: skip them
      float o = oimg[(size_t)r * W + gc];
      sum_so += nx * o;
      sum_s  += nx;
    }
    xc = xp; xp = xn;
    e_m = e_c; e_c = e_p;
  }
  #pragma unroll
  for (int o = 32; o; o >>= 1) {
    sum_so += __shfl_down(sum_so, o, 64);
    sum_s  += __shfl_down(sum_s, o, 64);
  }
  if (lane == 0) {
    atomicAdd(&g_acc[img * 4 + accBase],     sum_so);
    atomicAdd(&g_acc[img * 4 + accBase + 1], sum_s);
  }
}

// Global dice sums: g_acc[256..258] += {sum(p*t), sum(p), sum(t)}
__global__ __launch_bounds__(256) void dice_reduce(
    const float* __restrict__ pred, const float* __restrict__ target) {
  const float4* p4 = (const float4*)pred;
  const float4* t4 = (const float4*)target;
  const int n4 = NIMG * IMG_ELEMS / 4;
  float v0 = 0, v1 = 0, v2 = 0;
  for (int i = blockIdx.x * blockDim.x + threadIdx.x; i < n4;
       i += gridDim.x * blockDim.x) {
    float4 p = p4[i], t = t4[i];
    v0 += p.x * t.x + p.y * t.y + p.z * t.z + p.w * t.w;
    v1 += p.x + p.y + p.z + p.w;
    v2 += t.x + t.y + t.z + t.w;
  }
  #pragma unroll
  for (int o = 32; o; o >>= 1) {
    v0 += __shfl_down(v0, o, 64);
    v1 += __shfl_down(v1, o, 64);
    v2 += __shfl_down(v2, o, 64);
  }
  __shared__ float red[4][3];
  const int wave = threadIdx.x >> 6, lane = threadIdx.x & 63;
  if (lane == 0) { red[wave][0] = v0; red[wave][1] = v1; red[wave][2] = v2; }
  __syncthreads();
  if (threadIdx.x < 3) {
    float s = red[0][threadIdx.x] + red[1][threadIdx.x] +
              red[2][threadIdx.x] + red[3][threadIdx.x];
    atomicAdd(&g_acc[NIMG * 4 + threadIdx.x], s);
  }
}

__global__ void zero_acc() {
  for (int i = threadIdx.x; i < NACC; i += 256) g_acc[i] = 0.0f;
}

__global__ void final_kernel(float* __restrict__ out) {
  const int lane = threadIdx.x;  // 64 threads = 64 images
  float s1 = g_acc[lane * 4 + 0], s2 = g_acc[lane * 4 + 1];
  float s3 = g_acc[lane * 4 + 2], s4 = g_acc[lane * 4 + 3];
  float iflat = (s1 + 1.0f) / (s2 + 1.0f);
  float tflat = (s3 + 1.0f) / (s4 + 1.0f);
  float prod = iflat * tflat;
  float ssum = iflat + tflat;
  #pragma unroll
  for (int o = 32; o; o >>= 1) {
    prod += __shfl_down(prod, o, 64);
    ssum += __shfl_down(ssum, o, 64);
  }
  if (lane == 0) {
    float cldice = 1.0f - 2.0f * prod / ssum;
    float g1 = g_acc[NIMG * 4 + 0], g2 = g_acc[NIMG * 4 + 1],
          g3 = g_acc[NIMG * 4 + 2];
    float dice = 1.0f - (2.0f * g1 + 1e-6f) / (g2 + g3 + 1e-6f);
    out[0] = 0.8f * dice + 0.2f * cldice;
  }
}

extern "C" void kernel_launch(void* const* d_in, const int* in_sizes, int n_in,
                              void* d_out, int out_size, void* d_ws, size_t ws_size,
                              hipStream_t stream) {
  const float* pred   = (const float*)d_in[0];
  const float* target = (const float*)d_in[1];
  float* out = (float*)d_out;
  (void)d_ws; (void)ws_size;   // deliberately unused (R1/R2 lesson)

  const int nblocks = NIMG * WAVES_PER_IMG / 4;       // 576 blocks of 4 waves

  zero_acc<<<1, 256, 0, stream>>>();
  dice_reduce<<<256, 256, 0, stream>>>(pred, target);

  // pred chain: iters 0..8 ping-pong (ends in g_A), iter9 fused w/ reduction
  skel_iter<<<nblocks, 256, 0, stream>>>(pred, SEL_EXT, SEL_A);
  for (int k = 1; k <= 8; ++k) {
    if (k & 1) skel_iter<<<nblocks, 256, 0, stream>>>(nullptr, SEL_A, SEL_B);
    else       skel_iter<<<nblocks, 256, 0, stream>>>(nullptr, SEL_B, SEL_A);
  }
  skel_iter9_reduce<<<nblocks, 256, 0, stream>>>(target, 0);

  // target chain
  skel_iter<<<nblocks, 256, 0, stream>>>(target, SEL_EXT, SEL_A);
  for (int k = 1; k <= 8; ++k) {
    if (k & 1) skel_iter<<<nblocks, 256, 0, stream>>>(nullptr, SEL_A, SEL_B);
    else       skel_iter<<<nblocks, 256, 0, stream>>>(nullptr, SEL_B, SEL_A);
  }
  skel_iter9_reduce<<<nblocks, 256, 0, stream>>>(pred, 2);

  final_kernel<<<1, 64, 0, stream>>>(out);
}

// Round 5
// 628.795 us; speedup vs baseline: 2.1917x; 2.1917x over previous
//
#include <hip/hip_runtime.h>

// 0.8*dice_loss(pred,target) + 0.2*soft_cldice_loss(pred,target)
// pred/target: (64,1,512,512) fp32 -> 1 fp32 scalar.
//
// soft_skeletonize = 10x: x = relu(x - relu(dil3(ero3(x)) - ero3(x)))
//   ero3 = 3x3 min-pool, x OOB -> +inf; dil3 = 3x3 max-pool, ero OOB -> -inf
//
// R4 was latency-bound (1.1 TB/s, 22% occupancy, scalar loads). R5: each
// lane owns 8 contiguous cols (2x float4), one wave spans the full 512-wide
// row (no horizontal halo), 32 row-strips/image (2048 waves), explicit
// prefetch, rolling pair-min/max vertical windows.
//
// Hard-won harness rules: d_ws too small -> state in __device__ BSS;
// never pass __device__ symbols as host-side kernel args (host shadow addr).

#define H 512
#define W 512
#define NIMG 64
#define IMG_ELEMS (H * W)
#define RSTRIPS 32
#define SROWS (H / RSTRIPS)          // 16 output rows per wave
#define NACC (NIMG * 4 + 3)

__device__ float g_A[(size_t)NIMG * IMG_ELEMS];
__device__ float g_B[(size_t)NIMG * IMG_ELEMS];
__device__ float g_acc[NACC];

#define SEL_EXT 0
#define SEL_A 2
#define SEL_B 3

struct F8 { float4 a, b; };          // 8 consecutive columns per lane

__device__ __forceinline__ F8 f8fill(float v) {
  F8 r; r.a = make_float4(v, v, v, v); r.b = r.a; return r;
}
__device__ __forceinline__ F8 f8min(const F8& x, const F8& y) {
  F8 r;
  r.a.x = fminf(x.a.x, y.a.x); r.a.y = fminf(x.a.y, y.a.y);
  r.a.z = fminf(x.a.z, y.a.z); r.a.w = fminf(x.a.w, y.a.w);
  r.b.x = fminf(x.b.x, y.b.x); r.b.y = fminf(x.b.y, y.b.y);
  r.b.z = fminf(x.b.z, y.b.z); r.b.w = fminf(x.b.w, y.b.w);
  return r;
}
__device__ __forceinline__ F8 f8max(const F8& x, const F8& y) {
  F8 r;
  r.a.x = fmaxf(x.a.x, y.a.x); r.a.y = fmaxf(x.a.y, y.a.y);
  r.a.z = fmaxf(x.a.z, y.a.z); r.a.w = fmaxf(x.a.w, y.a.w);
  r.b.x = fmaxf(x.b.x, y.b.x); r.b.y = fmaxf(x.b.y, y.b.y);
  r.b.z = fmaxf(x.b.z, y.b.z); r.b.w = fmaxf(x.b.w, y.b.w);
  return r;
}
// horizontal 3-tap min over 8 cols; L/R image edges see +inf (x padding)
__device__ __forceinline__ F8 ero8(const F8& v, int lane) {
  float L = __shfl_up(v.b.w, 1, 64);
  if (lane == 0) L = __builtin_inff();
  float R = __shfl_down(v.a.x, 1, 64);
  if (lane == 63) R = __builtin_inff();
  F8 e;
  e.a.x = fminf(L,     fminf(v.a.x, v.a.y));
  e.a.y = fminf(v.a.x, fminf(v.a.y, v.a.z));
  e.a.z = fminf(v.a.y, fminf(v.a.z, v.a.w));
  e.a.w = fminf(v.a.z, fminf(v.a.w, v.b.x));
  e.b.x = fminf(v.a.w, fminf(v.b.x, v.b.y));
  e.b.y = fminf(v.b.x, fminf(v.b.y, v.b.z));
  e.b.z = fminf(v.b.y, fminf(v.b.z, v.b.w));
  e.b.w = fminf(v.b.z, fminf(v.b.w, R));
  return e;
}
// horizontal 3-tap max over 8 cols; edges see -inf (ero OOB position)
__device__ __forceinline__ F8 dil8(const F8& v, int lane) {
  float L = __shfl_up(v.b.w, 1, 64);
  if (lane == 0) L = -__builtin_inff();
  float R = __shfl_down(v.a.x, 1, 64);
  if (lane == 63) R = -__builtin_inff();
  F8 d;
  d.a.x = fmaxf(L,     fmaxf(v.a.x, v.a.y));
  d.a.y = fmaxf(v.a.x, fmaxf(v.a.y, v.a.z));
  d.a.z = fmaxf(v.a.y, fmaxf(v.a.z, v.a.w));
  d.a.w = fmaxf(v.a.z, fmaxf(v.a.w, v.b.x));
  d.b.x = fmaxf(v.a.w, fmaxf(v.b.x, v.b.y));
  d.b.y = fmaxf(v.b.x, fmaxf(v.b.y, v.b.z));
  d.b.z = fmaxf(v.b.y, fmaxf(v.b.z, v.b.w));
  d.b.w = fmaxf(v.b.z, fmaxf(v.b.w, R));
  return d;
}
__device__ __forceinline__ F8 f8relu_sub(const F8& x, const F8& y) {
  // relu(x - y)
  F8 r;
  r.a.x = fmaxf(x.a.x - y.a.x, 0.f); r.a.y = fmaxf(x.a.y - y.a.y, 0.f);
  r.a.z = fmaxf(x.a.z - y.a.z, 0.f); r.a.w = fmaxf(x.a.w - y.a.w, 0.f);
  r.b.x = fmaxf(x.b.x - y.b.x, 0.f); r.b.y = fmaxf(x.b.y - y.b.y, 0.f);
  r.b.z = fmaxf(x.b.z - y.b.z, 0.f); r.b.w = fmaxf(x.b.w - y.b.w, 0.f);
  return r;
}

// One skeletonize iteration over 64 images. src/dst chosen on DEVICE.
__global__ __launch_bounds__(256) void skel_iter(
    const float* __restrict__ ext, int srcSel, int dstSel) {
  const float* src = (srcSel == SEL_EXT) ? ext
                   : (srcSel == SEL_A)   ? (const float*)g_A : (const float*)g_B;
  float* dst = (dstSel == SEL_A) ? g_A : g_B;

  const int wid  = blockIdx.x * 4 + (threadIdx.x >> 6);
  const int lane = threadIdx.x & 63;
  const int img  = wid / RSTRIPS;
  const int rs   = wid % RSTRIPS;
  const int r0   = rs * SROWS;
  const float* simg = src + (size_t)img * IMG_ELEMS;
  float* dimg = dst + (size_t)img * IMG_ELEMS;
  const float PINF = __builtin_inff();

  auto loadrow = [&](int r) -> F8 {
    F8 v;
    if (r >= 0 && r < H) {
      const float4* rp = (const float4*)(simg + (size_t)r * W);
      v.a = rp[lane * 2];
      v.b = rp[lane * 2 + 1];
    } else {
      v = f8fill(PINF);
    }
    return v;
  };

  // prologue: rows r0-2 .. r0+2
  F8 xa = loadrow(r0 - 2);
  F8 xb = loadrow(r0 - 1);
  F8 xc = loadrow(r0);
  F8 xp = loadrow(r0 + 1);
  F8 xn = loadrow(r0 + 2);
  F8 em = ero8(f8min(xa, f8min(xb, xc)), lane);     // ero at r0-1
  if (r0 - 1 < 0) em = f8fill(-PINF);
  F8 ec = ero8(f8min(xb, f8min(xc, xp)), lane);     // ero at r0
  F8 pmaxA = f8max(em, ec);                         // max(e[r-1], e[r])
  F8 pminA = f8min(xc, xp);                         // min(x[r], x[r+1])

  #pragma unroll 4
  for (int r = r0; r < r0 + SROWS; ++r) {
    F8 xn2 = loadrow(r + 3);                        // prefetch next row
    F8 ep = ero8(f8min(pminA, xn), lane);           // ero at r+1
    if (r + 1 >= H) ep = f8fill(-PINF);
    F8 dil = dil8(f8max(pmaxA, ep), lane);
    F8 contour = f8relu_sub(dil, ec);
    F8 out = f8relu_sub(xc, contour);
    float4* op = (float4*)(dimg + (size_t)r * W);
    op[lane * 2]     = out.a;
    op[lane * 2 + 1] = out.b;
    pminA = f8min(xp, xn);
    pmaxA = f8max(ec, ep);
    xc = xp; xp = xn; xn = xn2; ec = ep;
  }
}

// Final skeletonize iteration (src = g_A) fused with pairing reduction:
//   g_acc[img*4+accBase] += sum(skel*other); g_acc[img*4+accBase+1] += sum(skel)
__global__ __launch_bounds__(256) void skel_iter9_reduce(
    const float* __restrict__ other, int accBase) {
  const int wid  = blockIdx.x * 4 + (threadIdx.x >> 6);
  const int lane = threadIdx.x & 63;
  const int img  = wid / RSTRIPS;
  const int rs   = wid % RSTRIPS;
  const int r0   = rs * SROWS;
  const float* simg = (const float*)g_A + (size_t)img * IMG_ELEMS;
  const float* oimg = other + (size_t)img * IMG_ELEMS;
  const float PINF = __builtin_inff();

  auto loadrow = [&](int r) -> F8 {
    F8 v;
    if (r >= 0 && r < H) {
      const float4* rp = (const float4*)(simg + (size_t)r * W);
      v.a = rp[lane * 2];
      v.b = rp[lane * 2 + 1];
    } else {
      v = f8fill(PINF);
    }
    return v;
  };

  F8 xa = loadrow(r0 - 2);
  F8 xb = loadrow(r0 - 1);
  F8 xc = loadrow(r0);
  F8 xp = loadrow(r0 + 1);
  F8 xn = loadrow(r0 + 2);
  F8 em = ero8(f8min(xa, f8min(xb, xc)), lane);
  if (r0 - 1 < 0) em = f8fill(-PINF);
  F8 ec = ero8(f8min(xb, f8min(xc, xp)), lane);
  F8 pmaxA = f8max(em, ec);
  F8 pminA = f8min(xc, xp);

  float sum_so = 0.0f, sum_s = 0.0f;
  #pragma unroll 4
  for (int r = r0; r < r0 + SROWS; ++r) {
    F8 xn2 = loadrow(r + 3);
    const float4* orp = (const float4*)(oimg + (size_t)r * W);
    float4 oa = orp[lane * 2];
    float4 ob = orp[lane * 2 + 1];
    F8 ep = ero8(f8min(pminA, xn), lane);
    if (r + 1 >= H) ep = f8fill(-PINF);
    F8 dil = dil8(f8max(pmaxA, ep), lane);
    F8 contour = f8relu_sub(dil, ec);
    F8 out = f8relu_sub(xc, contour);
    sum_so += out.a.x * oa.x + out.a.y * oa.y + out.a.z * oa.z + out.a.w * oa.w
            + out.b.x * ob.x + out.b.y * ob.y + out.b.z * ob.z + out.b.w * ob.w;
    sum_s  += out.a.x + out.a.y + out.a.z + out.a.w
            + out.b.x + out.b.y + out.b.z + out.b.w;
    pminA = f8min(xp, xn);
    pmaxA = f8max(ec, ep);
    xc = xp; xp = xn; xn = xn2; ec = ep;
  }
  #pragma unroll
  for (int o = 32; o; o >>= 1) {
    sum_so += __shfl_down(sum_so, o, 64);
    sum_s  += __shfl_down(sum_s, o, 64);
  }
  if (lane == 0) {
    atomicAdd(&g_acc[img * 4 + accBase],     sum_so);
    atomicAdd(&g_acc[img * 4 + accBase + 1], sum_s);
  }
}

// Global dice sums: g_acc[256..258] += {sum(p*t), sum(p), sum(t)}
__global__ __launch_bounds__(256) void dice_reduce(
    const float* __restrict__ pred, const float* __restrict__ target) {
  const float4* p4 = (const float4*)pred;
  const float4* t4 = (const float4*)target;
  const int n4 = NIMG * IMG_ELEMS / 4;
  float v0 = 0, v1 = 0, v2 = 0;
  for (int i = blockIdx.x * blockDim.x + threadIdx.x; i < n4;
       i += gridDim.x * blockDim.x) {
    float4 p = p4[i], t = t4[i];
    v0 += p.x * t.x + p.y * t.y + p.z * t.z + p.w * t.w;
    v1 += p.x + p.y + p.z + p.w;
    v2 += t.x + t.y + t.z + t.w;
  }
  #pragma unroll
  for (int o = 32; o; o >>= 1) {
    v0 += __shfl_down(v0, o, 64);
    v1 += __shfl_down(v1, o, 64);
    v2 += __shfl_down(v2, o, 64);
  }
  __shared__ float red[4][3];
  const int wave = threadIdx.x >> 6, lane = threadIdx.x & 63;
  if (lane == 0) { red[wave][0] = v0; red[wave][1] = v1; red[wave][2] = v2; }
  __syncthreads();
  if (threadIdx.x < 3) {
    float s = red[0][threadIdx.x] + red[1][threadIdx.x] +
              red[2][threadIdx.x] + red[3][threadIdx.x];
    atomicAdd(&g_acc[NIMG * 4 + threadIdx.x], s);
  }
}

__global__ void zero_acc() {
  for (int i = threadIdx.x; i < NACC; i += 256) g_acc[i] = 0.0f;
}

__global__ void final_kernel(float* __restrict__ out) {
  const int lane = threadIdx.x;  // 64 threads = 64 images
  float s1 = g_acc[lane * 4 + 0], s2 = g_acc[lane * 4 + 1];
  float s3 = g_acc[lane * 4 + 2], s4 = g_acc[lane * 4 + 3];
  float iflat = (s1 + 1.0f) / (s2 + 1.0f);
  float tflat = (s3 + 1.0f) / (s4 + 1.0f);
  float prod = iflat * tflat;
  float ssum = iflat + tflat;
  #pragma unroll
  for (int o = 32; o; o >>= 1) {
    prod += __shfl_down(prod, o, 64);
    ssum += __shfl_down(ssum, o, 64);
  }
  if (lane == 0) {
    float cldice = 1.0f - 2.0f * prod / ssum;
    float g1 = g_acc[NIMG * 4 + 0], g2 = g_acc[NIMG * 4 + 1],
          g3 = g_acc[NIMG * 4 + 2];
    float dice = 1.0f - (2.0f * g1 + 1e-6f) / (g2 + g3 + 1e-6f);
    out[0] = 0.8f * dice + 0.2f * cldice;
  }
}

extern "C" void kernel_launch(void* const* d_in, const int* in_sizes, int n_in,
                              void* d_out, int out_size, void* d_ws, size_t ws_size,
                              hipStream_t stream) {
  const float* pred   = (const float*)d_in[0];
  const float* target = (const float*)d_in[1];
  float* out = (float*)d_out;
  (void)d_ws; (void)ws_size;

  const int nblocks = NIMG * RSTRIPS / 4;   // 512 blocks of 4 waves

  zero_acc<<<1, 256, 0, stream>>>();
  dice_reduce<<<512, 256, 0, stream>>>(pred, target);

  // pred chain: iters 0..8 ping-pong (ends in g_A), iter9 fused w/ reduction
  skel_iter<<<nblocks, 256, 0, stream>>>(pred, SEL_EXT, SEL_A);
  for (int k = 1; k <= 8; ++k) {
    if (k & 1) skel_iter<<<nblocks, 256, 0, stream>>>(nullptr, SEL_A, SEL_B);
    else       skel_iter<<<nblocks, 256, 0, stream>>>(nullptr, SEL_B, SEL_A);
  }
  skel_iter9_reduce<<<nblocks, 256, 0, stream>>>(target, 0);

  // target chain
  skel_iter<<<nblocks, 256, 0, stream>>>(target, SEL_EXT, SEL_A);
  for (int k = 1; k <= 8; ++k) {
    if (k & 1) skel_iter<<<nblocks, 256, 0, stream>>>(nullptr, SEL_A, SEL_B);
    else       skel_iter<<<nblocks, 256, 0, stream>>>(nullptr, SEL_B, SEL_A);
  }
  skel_iter9_reduce<<<nblocks, 256, 0, stream>>>(pred, 2);

  final_kernel<<<1, 64, 0, stream>>>(out);
}

// Round 6
// 488.241 us; speedup vs baseline: 2.8226x; 1.2879x over previous
//
#include <hip/hip_runtime.h>

// 0.8*dice_loss(pred,target) + 0.2*soft_cldice_loss(pred,target)
// pred/target: (64,1,512,512) fp32 -> 1 fp32 scalar.
//
// soft_skeletonize = 10x: x = relu(x - relu(dil3(ero3(x)) - ero3(x)))
//   ero3 = 3x3 min-pool, x OOB -> +inf; dil3 = 3x3 max-pool, ero OOB -> -inf
//
// R6: TWO skeletonize iterations fused per pass (register-pipelined stages,
// +-4 row halo), dice fused into pred pass 1. 5 passes per chain instead of
// 10 + standalone dice: ~1.5 GiB total traffic vs 2.7 GiB in R5.
//
// Harness rules learned: d_ws too small -> state in __device__ BSS;
// never pass __device__ symbols as host-side kernel args (host shadow addr).

#define H 512
#define W 512
#define NIMG 64
#define IMG_ELEMS (H * W)
#define RSTRIPS 32
#define SROWS (H / RSTRIPS)          // 16 output rows per wave
#define NACC (NIMG * 4 + 3)

__device__ float g_A[(size_t)NIMG * IMG_ELEMS];
__device__ float g_B[(size_t)NIMG * IMG_ELEMS];
__device__ float g_acc[NACC];

#define SEL_EXT 0
#define SEL_A 2
#define SEL_B 3

struct F8 { float4 a, b; };          // 8 consecutive columns per lane

__device__ __forceinline__ F8 f8fill(float v) {
  F8 r; r.a = make_float4(v, v, v, v); r.b = r.a; return r;
}
__device__ __forceinline__ F8 f8min(const F8& x, const F8& y) {
  F8 r;
  r.a.x = fminf(x.a.x, y.a.x); r.a.y = fminf(x.a.y, y.a.y);
  r.a.z = fminf(x.a.z, y.a.z); r.a.w = fminf(x.a.w, y.a.w);
  r.b.x = fminf(x.b.x, y.b.x); r.b.y = fminf(x.b.y, y.b.y);
  r.b.z = fminf(x.b.z, y.b.z); r.b.w = fminf(x.b.w, y.b.w);
  return r;
}
__device__ __forceinline__ F8 f8max(const F8& x, const F8& y) {
  F8 r;
  r.a.x = fmaxf(x.a.x, y.a.x); r.a.y = fmaxf(x.a.y, y.a.y);
  r.a.z = fmaxf(x.a.z, y.a.z); r.a.w = fmaxf(x.a.w, y.a.w);
  r.b.x = fmaxf(x.b.x, y.b.x); r.b.y = fmaxf(x.b.y, y.b.y);
  r.b.z = fmaxf(x.b.z, y.b.z); r.b.w = fmaxf(x.b.w, y.b.w);
  return r;
}
// horizontal 3-tap min; L/R image edges see +inf
__device__ __forceinline__ F8 ero8(const F8& v, int lane) {
  float L = __shfl_up(v.b.w, 1, 64);
  if (lane == 0) L = __builtin_inff();
  float R = __shfl_down(v.a.x, 1, 64);
  if (lane == 63) R = __builtin_inff();
  F8 e;
  e.a.x = fminf(L,     fminf(v.a.x, v.a.y));
  e.a.y = fminf(v.a.x, fminf(v.a.y, v.a.z));
  e.a.z = fminf(v.a.y, fminf(v.a.z, v.a.w));
  e.a.w = fminf(v.a.z, fminf(v.a.w, v.b.x));
  e.b.x = fminf(v.a.w, fminf(v.b.x, v.b.y));
  e.b.y = fminf(v.b.x, fminf(v.b.y, v.b.z));
  e.b.z = fminf(v.b.y, fminf(v.b.z, v.b.w));
  e.b.w = fminf(v.b.z, fminf(v.b.w, R));
  return e;
}
// horizontal 3-tap max; edges see -inf
__device__ __forceinline__ F8 dil8(const F8& v, int lane) {
  float L = __shfl_up(v.b.w, 1, 64);
  if (lane == 0) L = -__builtin_inff();
  float R = __shfl_down(v.a.x, 1, 64);
  if (lane == 63) R = -__builtin_inff();
  F8 d;
  d.a.x = fmaxf(L,     fmaxf(v.a.x, v.a.y));
  d.a.y = fmaxf(v.a.x, fmaxf(v.a.y, v.a.z));
  d.a.z = fmaxf(v.a.y, fmaxf(v.a.z, v.a.w));
  d.a.w = fmaxf(v.a.z, fmaxf(v.a.w, v.b.x));
  d.b.x = fmaxf(v.a.w, fmaxf(v.b.x, v.b.y));
  d.b.y = fmaxf(v.b.x, fmaxf(v.b.y, v.b.z));
  d.b.z = fmaxf(v.b.y, fmaxf(v.b.z, v.b.w));
  d.b.w = fmaxf(v.b.z, fmaxf(v.b.w, R));
  return d;
}
__device__ __forceinline__ F8 f8relu_sub(const F8& x, const F8& y) {
  F8 r;
  r.a.x = fmaxf(x.a.x - y.a.x, 0.f); r.a.y = fmaxf(x.a.y - y.a.y, 0.f);
  r.a.z = fmaxf(x.a.z - y.a.z, 0.f); r.a.w = fmaxf(x.a.w - y.a.w, 0.f);
  r.b.x = fmaxf(x.b.x - y.b.x, 0.f); r.b.y = fmaxf(x.b.y - y.b.y, 0.f);
  r.b.z = fmaxf(x.b.z - y.b.z, 0.f); r.b.w = fmaxf(x.b.w - y.b.w, 0.f);
  return r;
}
__device__ __forceinline__ float f8dot(const F8& x, const float4& oa,
                                       const float4& ob) {
  return x.a.x * oa.x + x.a.y * oa.y + x.a.z * oa.z + x.a.w * oa.w
       + x.b.x * ob.x + x.b.y * ob.y + x.b.z * ob.z + x.b.w * ob.w;
}
__device__ __forceinline__ float f8sum(const F8& x) {
  return x.a.x + x.a.y + x.a.z + x.a.w + x.b.x + x.b.y + x.b.z + x.b.w;
}

// Two fused skeletonize iterations (register-pipelined).
// MODE 0: store z to dimg.
// MODE 1: store z + accumulate dice sums over (simg, oimg) rows.
// MODE 2: no store; accumulate sum(z*other), sum(z) into g_acc[img*4+accBase].
template <int MODE>
__device__ __forceinline__ void skel2_core(
    const float* __restrict__ simg, float* __restrict__ dimg,
    const float* __restrict__ oimg, int img, int r0, int lane, int accBase) {
  const float PINF = __builtin_inff();

  auto loadrow = [&](int r) -> F8 {
    F8 v;
    if (r >= 0 && r < H) {
      const float4* rp = (const float4*)(simg + (size_t)r * W);
      v.a = rp[lane * 2];
      v.b = rp[lane * 2 + 1];
    } else {
      v = f8fill(PINF);
    }
    return v;
  };

  // ---- stage-1 rolling state, positioned to emit y[s] next; s = r0-2 ----
  int s = r0 - 2;
  F8 xa = loadrow(s - 2);
  F8 xb = loadrow(s - 1);
  F8 xc = loadrow(s);
  F8 xp = loadrow(s + 1);
  F8 xn = loadrow(s + 2);
  F8 em = ero8(f8min(xa, f8min(xb, xc)), lane);      // e[s-1]
  if (s - 1 < 0) em = f8fill(-PINF);
  F8 ec = ero8(f8min(xb, f8min(xc, xp)), lane);      // e[s]
  if (s < 0) ec = f8fill(-PINF);
  F8 pmaxA = f8max(em, ec);
  F8 pminA = f8min(xc, xp);

  auto step1 = [&]() -> F8 {                         // emits y[s], s++
    F8 ep = ero8(f8min(pminA, xn), lane);            // e[s+1]
    if (s + 1 < 0 || s + 1 >= H) ep = f8fill(-PINF);
    F8 dil = dil8(f8max(pmaxA, ep), lane);
    F8 y = f8relu_sub(xc, f8relu_sub(dil, ec));
    if (s < 0 || s >= H) y = f8fill(PINF);           // stage-2 sees +inf OOB
    pminA = f8min(xp, xn);
    pmaxA = f8max(ec, ep);
    xc = xp; xp = xn; xn = loadrow(s + 3);
    ec = ep;
    ++s;
    return y;
  };

  // ---- stage-2 warmup: y rows r0-2 .. r0+2 ----
  F8 ya = step1();
  F8 yb = step1();
  F8 yc = step1();
  F8 yp = step1();
  F8 yn = step1();
  F8 e2m = ero8(f8min(ya, f8min(yb, yc)), lane);     // e2[r0-1]
  if (r0 - 1 < 0) e2m = f8fill(-PINF);
  F8 e2c = ero8(f8min(yb, f8min(yc, yp)), lane);     // e2[r0]
  F8 pmax2 = f8max(e2m, e2c);
  F8 pmin2 = f8min(yc, yp);

  float s_so = 0.f, s_s = 0.f;                       // MODE 2
  float v_pt = 0.f, v_p = 0.f, v_t = 0.f;            // MODE 1

  #pragma unroll 2
  for (int t = r0; t < r0 + SROWS; ++t) {
    F8 ynew = step1();                               // y[t+3]
    F8 e2p = ero8(f8min(pmin2, yn), lane);           // e2[t+1]
    if (t + 1 >= H) e2p = f8fill(-PINF);
    F8 d2 = dil8(f8max(pmax2, e2p), lane);
    F8 z = f8relu_sub(yc, f8relu_sub(d2, e2c));

    if (MODE == 2) {
      const float4* orp = (const float4*)(oimg + (size_t)t * W);
      float4 oa = orp[lane * 2];
      float4 ob = orp[lane * 2 + 1];
      s_so += f8dot(z, oa, ob);
      s_s  += f8sum(z);
    } else {
      float4* op = (float4*)(dimg + (size_t)t * W);
      op[lane * 2]     = z.a;
      op[lane * 2 + 1] = z.b;
      if (MODE == 1) {                               // dice: raw p,t rows
        const float4* prp = (const float4*)(simg + (size_t)t * W);
        const float4* trp = (const float4*)(oimg + (size_t)t * W);
        float4 pa = prp[lane * 2], pb = prp[lane * 2 + 1];
        float4 ta = trp[lane * 2], tb = trp[lane * 2 + 1];
        v_pt += pa.x * ta.x + pa.y * ta.y + pa.z * ta.z + pa.w * ta.w
              + pb.x * tb.x + pb.y * tb.y + pb.z * tb.z + pb.w * tb.w;
        v_p  += pa.x + pa.y + pa.z + pa.w + pb.x + pb.y + pb.z + pb.w;
        v_t  += ta.x + ta.y + ta.z + ta.w + tb.x + tb.y + tb.z + tb.w;
      }
    }
    pmin2 = f8min(yp, yn);
    pmax2 = f8max(e2c, e2p);
    yc = yp; yp = yn; yn = ynew; e2c = e2p;
  }

  if (MODE == 2) {
    #pragma unroll
    for (int o = 32; o; o >>= 1) {
      s_so += __shfl_down(s_so, o, 64);
      s_s  += __shfl_down(s_s, o, 64);
    }
    if (lane == 0) {
      atomicAdd(&g_acc[img * 4 + accBase],     s_so);
      atomicAdd(&g_acc[img * 4 + accBase + 1], s_s);
    }
  }
  if (MODE == 1) {
    #pragma unroll
    for (int o = 32; o; o >>= 1) {
      v_pt += __shfl_down(v_pt, o, 64);
      v_p  += __shfl_down(v_p, o, 64);
      v_t  += __shfl_down(v_t, o, 64);
    }
    if (lane == 0) {
      atomicAdd(&g_acc[NIMG * 4 + 0], v_pt);
      atomicAdd(&g_acc[NIMG * 4 + 1], v_p);
      atomicAdd(&g_acc[NIMG * 4 + 2], v_t);
    }
  }
}

__global__ __launch_bounds__(256) void skel2_plain(
    const float* __restrict__ ext, int srcSel, int dstSel) {
  const float* src = (srcSel == SEL_EXT) ? ext
                   : (srcSel == SEL_A)   ? (const float*)g_A : (const float*)g_B;
  float* dst = (dstSel == SEL_A) ? g_A : g_B;
  const int wid  = blockIdx.x * 4 + (threadIdx.x >> 6);
  const int lane = threadIdx.x & 63;
  const int img  = wid / RSTRIPS;
  const int r0   = (wid % RSTRIPS) * SROWS;
  skel2_core<0>(src + (size_t)img * IMG_ELEMS, dst + (size_t)img * IMG_ELEMS,
                nullptr, img, r0, lane, 0);
}

// pred pass 1: pred -> g_A (iters 0,1) + global dice sums over (pred, target)
__global__ __launch_bounds__(256) void skel2_dice(
    const float* __restrict__ pred, const float* __restrict__ target) {
  const int wid  = blockIdx.x * 4 + (threadIdx.x >> 6);
  const int lane = threadIdx.x & 63;
  const int img  = wid / RSTRIPS;
  const int r0   = (wid % RSTRIPS) * SROWS;
  skel2_core<1>(pred + (size_t)img * IMG_ELEMS,
                (float*)g_A + (size_t)img * IMG_ELEMS,
                target + (size_t)img * IMG_ELEMS, img, r0, lane, 0);
}

// pass 5: g_B -> (iters 8,9) fused with pairing reduction vs `other`
__global__ __launch_bounds__(256) void skel2_reduce(
    const float* __restrict__ other, int accBase) {
  const int wid  = blockIdx.x * 4 + (threadIdx.x >> 6);
  const int lane = threadIdx.x & 63;
  const int img  = wid / RSTRIPS;
  const int r0   = (wid % RSTRIPS) * SROWS;
  skel2_core<2>((const float*)g_B + (size_t)img * IMG_ELEMS, nullptr,
                other + (size_t)img * IMG_ELEMS, img, r0, lane, accBase);
}

__global__ void zero_acc() {
  for (int i = threadIdx.x; i < NACC; i += 256) g_acc[i] = 0.0f;
}

__global__ void final_kernel(float* __restrict__ out) {
  const int lane = threadIdx.x;  // 64 threads = 64 images
  float s1 = g_acc[lane * 4 + 0], s2 = g_acc[lane * 4 + 1];
  float s3 = g_acc[lane * 4 + 2], s4 = g_acc[lane * 4 + 3];
  float iflat = (s1 + 1.0f) / (s2 + 1.0f);
  float tflat = (s3 + 1.0f) / (s4 + 1.0f);
  float prod = iflat * tflat;
  float ssum = iflat + tflat;
  #pragma unroll
  for (int o = 32; o; o >>= 1) {
    prod += __shfl_down(prod, o, 64);
    ssum += __shfl_down(ssum, o, 64);
  }
  if (lane == 0) {
    float cldice = 1.0f - 2.0f * prod / ssum;
    float g1 = g_acc[NIMG * 4 + 0], g2 = g_acc[NIMG * 4 + 1],
          g3 = g_acc[NIMG * 4 + 2];
    float dice = 1.0f - (2.0f * g1 + 1e-6f) / (g2 + g3 + 1e-6f);
    out[0] = 0.8f * dice + 0.2f * cldice;
  }
}

extern "C" void kernel_launch(void* const* d_in, const int* in_sizes, int n_in,
                              void* d_out, int out_size, void* d_ws, size_t ws_size,
                              hipStream_t stream) {
  const float* pred   = (const float*)d_in[0];
  const float* target = (const float*)d_in[1];
  float* out = (float*)d_out;
  (void)d_ws; (void)ws_size;

  const int nblocks = NIMG * RSTRIPS / 4;   // 512 blocks of 4 waves

  zero_acc<<<1, 256, 0, stream>>>();

  // pred chain: iters (0,1) w/ dice -> A; (2,3) A->B; (4,5) B->A; (6,7) A->B;
  // (8,9) B -> fused reduce vs target
  skel2_dice<<<nblocks, 256, 0, stream>>>(pred, target);
  skel2_plain<<<nblocks, 256, 0, stream>>>(nullptr, SEL_A, SEL_B);
  skel2_plain<<<nblocks, 256, 0, stream>>>(nullptr, SEL_B, SEL_A);
  skel2_plain<<<nblocks, 256, 0, stream>>>(nullptr, SEL_A, SEL_B);
  skel2_reduce<<<nblocks, 256, 0, stream>>>(target, 0);

  // target chain
  skel2_plain<<<nblocks, 256, 0, stream>>>(target, SEL_EXT, SEL_A);
  skel2_plain<<<nblocks, 256, 0, stream>>>(nullptr, SEL_A, SEL_B);
  skel2_plain<<<nblocks, 256, 0, stream>>>(nullptr, SEL_B, SEL_A);
  skel2_plain<<<nblocks, 256, 0, stream>>>(nullptr, SEL_A, SEL_B);
  skel2_reduce<<<nblocks, 256, 0, stream>>>(pred, 2);

  final_kernel<<<1, 64, 0, stream>>>(out);
}